// Round 5
// baseline (107.813 us; speedup 1.0000x reference)
//
#include <hip/hip_runtime.h>
#include <hip/hip_fp16.h>
#include <cstdint>
#include <cstddef>

#define BATCH 8
#define NPTS  2048
#define CH1   64
#define CH2   128
#define NSAMP 64

typedef _Float16 half8v  __attribute__((ext_vector_type(8)));
typedef float    float4v __attribute__((ext_vector_type(4)));
typedef unsigned uint4v  __attribute__((ext_vector_type(4)));

__device__ inline unsigned pkmax(unsigned a, unsigned b) {
  unsigned d;
  asm("v_pk_max_f16 %0, %1, %2" : "=v"(d) : "v"(a), "v"(b));
  return d;
}

// ---------------------------------------------------------------------------
// Kernel 1: per-point MLP via MFMA (128 x 16384 x 64 fp16 GEMM).
// 512 blocks x 256 threads; wave = (point-tile, m-half): each wave computes
// 4 m-tiles (64 output channels) of one 16-point tile -> 2048 waves, 2/SIMD
// (vs R4's 1/SIMD with the full-W2 prologue). W2 fragments in VGPRs.
// Also emits xyzq[pt] = {x,y,z,|p|^2} for the query kernel.
// ---------------------------------------------------------------------------
__global__ __launch_bounds__(256) void mlp_kernel(
    const float* __restrict__ x,
    const float* __restrict__ W1, const float* __restrict__ b1,
    const float* __restrict__ W2, const float* __restrict__ b2,
    __half* __restrict__ h2, float4v* __restrict__ xyzq) {
  const int t = threadIdx.x;
  const int wave = t >> 6;
  const int lane = t & 63;
  const int n = lane & 15;          // point within tile (B/D column)
  const int quad = lane >> 4;       // 0..3
  const int pti = wave >> 1;        // which 16-point tile of the block (0/1)
  const int mh  = wave & 1;         // m-half: mtiles mh*4 .. mh*4+3
  const int base = blockIdx.x * 32; // 32 points per block

  // packed coord+norm table for the query kernel
  if (t < 32) {
    const int pt = base + t;
    const float X = x[pt * 3 + 0];
    const float Y = x[pt * 3 + 1];
    const float Z = x[pt * 3 + 2];
    float4v v;
    v[0] = X; v[1] = Y; v[2] = Z; v[3] = fmaf(Z, Z, fmaf(Y, Y, X * X));
    xyzq[pt] = v;
  }

  // W1 rows for this lane's 16 h1 channels: o = quad*8+j (j<8) and o+32
  float w1x[16], w1y[16], w1z[16], b1v[16];
#pragma unroll
  for (int j = 0; j < 16; ++j) {
    const int o = quad * 8 + (j & 7) + ((j < 8) ? 0 : 32);
    w1x[j] = W1[o * 3 + 0];
    w1y[j] = W1[o * 3 + 1];
    w1z[j] = W1[o * 3 + 2];
    b1v[j] = b1[o];
  }

  // W2 A-fragments (fp16) for this wave's 4 mtiles: afrag[mt][kfrag]
  half8v afrag[4][2];
  float4v bias[4];
#pragma unroll
  for (int mt = 0; mt < 4; ++mt) {
    const int mtg = mh * 4 + mt;
    const int m = mtg * 16 + n;
#pragma unroll
    for (int kf = 0; kf < 2; ++kf) {
      const float4v* wp = (const float4v*)(W2 + m * CH1 + kf * 32 + quad * 8);
      const float4v lo = wp[0];
      const float4v hi = wp[1];
#pragma unroll
      for (int e = 0; e < 4; ++e) {
        afrag[mt][kf][e]     = (_Float16)lo[e];
        afrag[mt][kf][4 + e] = (_Float16)hi[e];
      }
    }
    bias[mt] = *(const float4v*)(b2 + mtg * 16 + quad * 4);
  }

  // ---- layer 1 for this wave's point tile, packed as B fragments ----
  const int pt = base + pti * 16 + n;
  const float X = x[pt * 3 + 0];
  const float Y = x[pt * 3 + 1];
  const float Z = x[pt * 3 + 2];
  half8v bf0, bf1;
#pragma unroll
  for (int j = 0; j < 8; ++j) {
    const float ha = fmaxf(fmaf(w1z[j], Z, fmaf(w1y[j], Y, fmaf(w1x[j], X, b1v[j]))), 0.f);
    const float hb = fmaxf(fmaf(w1z[8 + j], Z, fmaf(w1y[8 + j], Y, fmaf(w1x[8 + j], X, b1v[8 + j]))), 0.f);
    bf0[j] = (_Float16)ha;
    bf1[j] = (_Float16)hb;
  }

  // ---- layer 2: 8 MFMA, epilogue relu + fp16 store (8 B per mtile) ----
  __half* hrow = h2 + (size_t)pt * CH2;
#pragma unroll
  for (int mt = 0; mt < 4; ++mt) {
    const int mtg = mh * 4 + mt;
    float4v acc = bias[mt];
    acc = __builtin_amdgcn_mfma_f32_16x16x32_f16(afrag[mt][0], bf0, acc, 0, 0, 0);
    acc = __builtin_amdgcn_mfma_f32_16x16x32_f16(afrag[mt][1], bf1, acc, 0, 0, 0);
    const int p0 = mtg * 16 + quad * 4;
    const __half2 lo2 = __halves2half2(__float2half(fmaxf(acc[0], 0.f)),
                                       __float2half(fmaxf(acc[1], 0.f)));
    const __half2 hi2 = __halves2half2(__float2half(fmaxf(acc[2], 0.f)),
                                       __float2half(fmaxf(acc[3], 0.f)));
    uint2 pk;
    pk.x = *(const unsigned*)&lo2;
    pk.y = *(const unsigned*)&hi2;
    *(uint2*)(hrow + p0) = pk;   // 8 B aligned: p0 = 16*mtg + 4*quad
  }
}

// ---------------------------------------------------------------------------
// Kernel 2: ball query + max-pool. One wave per query.
// Phase 1: chunks processed in groups of 4 with all 4 xq loads issued up
// front (early-exit only at group granularity; over-scan is guarded by
// pos < NSAMP). fp32 distance + fp64 guard band -> decisions bit-exact.
// Phase 2: all 8 list reads, then all 16 dwordx4 loads hoisted into arrays
// (~64 VGPRs in flight) BEFORE the pkmax tree -- R4's 32-VGPR serialization
// was the bottleneck. ds_swizzle butterfly for the cross-slot max.
// ---------------------------------------------------------------------------
__global__ __launch_bounds__(256, 4) void query_kernel(
    const float4v* __restrict__ xyzq,
    const __half* __restrict__ h2,
    float* __restrict__ out) {
  __shared__ int list[4][NSAMP];

  const int wave = threadIdx.x >> 6;
  const int lane = threadIdx.x & 63;
  const int q = blockIdx.x * 4 + wave;
  const int b = q >> 11;
  const int s = q & (NPTS - 1);

  const float4v* xq = xyzq + (size_t)b * NPTS;
  const float4v qv = xq[s];
  const float qx = qv[0], qy = qv[1], qz = qv[2], dqf = qv[3];
  const double dq = (double)qx * qx + (double)qy * qy + (double)qz * qz;
  const unsigned long long lt = (1ull << lane) - 1ull;

  // ---- Phase 1: first NSAMP in-radius hits, ascending index ----
  int count = 0;
  for (int g = 0; g < NPTS / 256 && count < NSAMP; ++g) {
    float4v pv[4];
#pragma unroll
    for (int j = 0; j < 4; ++j) pv[j] = xq[g * 256 + j * 64 + lane];
#pragma unroll
    for (int j = 0; j < 4; ++j) {
      const int m = g * 256 + j * 64 + lane;
      const float px = pv[j][0], py = pv[j][1], pz = pv[j][2];
      const float dot = fmaf(qz, pz, fmaf(qy, py, qx * px));
      const float dist = fmaf(-2.f, dot, dqf + pv[j][3]);
      bool hit;
      if (__ballot(__builtin_fabsf(dist - 0.36f) <= 3e-5f)) {
        // rare exact path: fp64, same evaluation as the np reference
        const double dm = (double)px * px + (double)py * py + (double)pz * pz;
        const double dd = (double)qx * px + (double)qy * py + (double)qz * pz;
        hit = !((dq + dm - 2.0 * dd) > 0.36);
      } else {
        hit = !(dist > 0.36f);
      }
      const unsigned long long mask = __ballot(hit);
      if (hit) {
        const int pos = count + __popcll(mask & lt);
        if (pos < NSAMP) list[wave][pos] = m;
      }
      count += __popcll(mask);
    }
  }
  if (count > NSAMP) count = NSAMP;
  const int first = list[wave][0];      // self is always a hit
  if (lane >= count) list[wave][lane] = first;

  // ---- Phase 2: lane = (hit-slot h, channel-slice c); loads fully hoisted ----
  const int h = lane & 7;    // hit slot within a round
  const int c = lane >> 3;   // 16-channel slice
  const char* hb = (const char*)h2 + (size_t)b * NPTS * CH2 * 2 + c * 32;

  int ms[8];
#pragma unroll
  for (int r = 0; r < 8; ++r) ms[r] = list[wave][r * 8 + h];

  uint4v va[8], vb[8];
#pragma unroll
  for (int r = 0; r < 8; ++r) {
    const char* p = hb + (size_t)ms[r] * 256;
    va[r] = *(const uint4v*)p;
    vb[r] = *(const uint4v*)(p + 16);
  }

  unsigned a0 = 0, a1 = 0, a2 = 0, a3 = 0, a4 = 0, a5 = 0, a6 = 0, a7 = 0;
#pragma unroll
  for (int r = 0; r < 8; ++r) {
    a0 = pkmax(a0, va[r][0]); a1 = pkmax(a1, va[r][1]);
    a2 = pkmax(a2, va[r][2]); a3 = pkmax(a3, va[r][3]);
    a4 = pkmax(a4, vb[r][0]); a5 = pkmax(a5, vb[r][1]);
    a6 = pkmax(a6, vb[r][2]); a7 = pkmax(a7, vb[r][3]);
  }

  // xor-butterfly over hit-slot bits (lane bits 0..2)
#define RED_STEP(IMM)                                                        \
  a0 = pkmax(a0, (unsigned)__builtin_amdgcn_ds_swizzle((int)a0, IMM));       \
  a1 = pkmax(a1, (unsigned)__builtin_amdgcn_ds_swizzle((int)a1, IMM));       \
  a2 = pkmax(a2, (unsigned)__builtin_amdgcn_ds_swizzle((int)a2, IMM));       \
  a3 = pkmax(a3, (unsigned)__builtin_amdgcn_ds_swizzle((int)a3, IMM));       \
  a4 = pkmax(a4, (unsigned)__builtin_amdgcn_ds_swizzle((int)a4, IMM));       \
  a5 = pkmax(a5, (unsigned)__builtin_amdgcn_ds_swizzle((int)a5, IMM));       \
  a6 = pkmax(a6, (unsigned)__builtin_amdgcn_ds_swizzle((int)a6, IMM));       \
  a7 = pkmax(a7, (unsigned)__builtin_amdgcn_ds_swizzle((int)a7, IMM));
  RED_STEP(0x041F)   // xor 1
  RED_STEP(0x081F)   // xor 2
  RED_STEP(0x101F)   // xor 4
#undef RED_STEP

  // lane writes half2 #h of its 16-channel slice
  const unsigned s1 = (h & 1) ? a1 : a0;
  const unsigned s2 = (h & 1) ? a3 : a2;
  const unsigned s3 = (h & 1) ? a5 : a4;
  const unsigned s4 = (h & 1) ? a7 : a6;
  const unsigned t1 = (h & 2) ? s2 : s1;
  const unsigned t2 = (h & 2) ? s4 : s3;
  const unsigned vsel = (h & 4) ? t2 : t1;
  const __half2 hv = *(const __half2*)&vsel;

  const int p0 = c * 16 + 2 * h;
  const size_t ob = (size_t)b * CH2 * NPTS;
  out[ob + (size_t)p0 * NPTS + s]       = __low2float(hv);
  out[ob + (size_t)(p0 + 1) * NPTS + s] = __high2float(hv);
}

// ---------------------------------------------------------------------------
extern "C" void kernel_launch(void* const* d_in, const int* in_sizes, int n_in,
                              void* d_out, int out_size, void* d_ws, size_t ws_size,
                              hipStream_t stream) {
  const float* x  = (const float*)d_in[0];
  const float* W1 = (const float*)d_in[1];
  const float* b1 = (const float*)d_in[2];
  const float* W2 = (const float*)d_in[3];
  const float* b2 = (const float*)d_in[4];
  float* out = (float*)d_out;

  __half*  h2   = (__half*)d_ws;                                     // 4 MB
  float4v* xyzq = (float4v*)((char*)d_ws + (size_t)4 * 1024 * 1024); // 256 KB

  mlp_kernel<<<(BATCH * NPTS) / 32, 256, 0, stream>>>(
      x, W1, b1, W2, b2, h2, xyzq);
  query_kernel<<<(BATCH * NPTS) / 4, 256, 0, stream>>>(xyzq, h2, out);
}

// Round 7
// 105.625 us; speedup vs baseline: 1.0207x; 1.0207x over previous
//
#include <hip/hip_runtime.h>
#include <hip/hip_fp16.h>
#include <cstdint>
#include <cstddef>

#define BATCH 8
#define NPTS  2048
#define CH1   64
#define CH2   128
#define NSAMP 64

typedef _Float16 half8v  __attribute__((ext_vector_type(8)));
typedef _Float16 half2v  __attribute__((ext_vector_type(2)));
typedef float    float4v __attribute__((ext_vector_type(4)));
typedef unsigned uint4v  __attribute__((ext_vector_type(4)));

// packed f16 max, compiler-visible (lowers to v_pk_max_f16; no inline asm so
// the scheduler can hoist loads across it)
__device__ inline unsigned pmax(unsigned a, unsigned b) {
  half2v ha = __builtin_bit_cast(half2v, a);
  half2v hb = __builtin_bit_cast(half2v, b);
  return __builtin_bit_cast(unsigned, __builtin_elementwise_max(ha, hb));
}

__device__ inline uint4v pk4max(uint4v a, uint4v b) {
  uint4v d;
#pragma unroll
  for (int i = 0; i < 4; ++i) d[i] = pmax(a[i], b[i]);
  return d;
}

__device__ inline float h2lo(unsigned u) {
  return (float)__builtin_bit_cast(half2v, u)[0];
}
__device__ inline float h2hi(unsigned u) {
  return (float)__builtin_bit_cast(half2v, u)[1];
}

// ---------------------------------------------------------------------------
// Kernel 1: per-point MLP via MFMA (128 x 16384 x 64 fp16 GEMM).
// Wave = (16-point tile, m-half); W2 fragments live in VGPRs; h1 computed
// in-register and packed directly as B fragments. Also emits
// xyzq[pt] = {x,y,z,|p|^2} for the query kernel's phase 1.
// ---------------------------------------------------------------------------
__global__ __launch_bounds__(256) void mlp_kernel(
    const float* __restrict__ x,
    const float* __restrict__ W1, const float* __restrict__ b1,
    const float* __restrict__ W2, const float* __restrict__ b2,
    __half* __restrict__ h2, float4v* __restrict__ xyzq) {
  const int t = threadIdx.x;
  const int wave = t >> 6;
  const int lane = t & 63;
  const int n = lane & 15;          // point within tile (B/D column)
  const int quad = lane >> 4;       // 0..3
  const int pti = wave >> 1;        // 16-point tile of the block (0/1)
  const int mh  = wave & 1;         // m-half: mtiles mh*4 .. mh*4+3
  const int base = blockIdx.x * 32; // 32 points per block

  if (t < 32) {
    const int pt = base + t;
    const float X = x[pt * 3 + 0];
    const float Y = x[pt * 3 + 1];
    const float Z = x[pt * 3 + 2];
    float4v v;
    v[0] = X; v[1] = Y; v[2] = Z; v[3] = fmaf(Z, Z, fmaf(Y, Y, X * X));
    xyzq[pt] = v;
  }

  // W1 rows for this lane's 16 h1 channels: o = quad*8+j (j<8) and o+32
  float w1x[16], w1y[16], w1z[16], b1v[16];
#pragma unroll
  for (int j = 0; j < 16; ++j) {
    const int o = quad * 8 + (j & 7) + ((j < 8) ? 0 : 32);
    w1x[j] = W1[o * 3 + 0];
    w1y[j] = W1[o * 3 + 1];
    w1z[j] = W1[o * 3 + 2];
    b1v[j] = b1[o];
  }

  // W2 A-fragments (fp16) for this wave's 4 mtiles
  half8v afrag[4][2];
  float4v bias[4];
#pragma unroll
  for (int mt = 0; mt < 4; ++mt) {
    const int mtg = mh * 4 + mt;
    const int m = mtg * 16 + n;
#pragma unroll
    for (int kf = 0; kf < 2; ++kf) {
      const float4v* wp = (const float4v*)(W2 + m * CH1 + kf * 32 + quad * 8);
      const float4v lo = wp[0];
      const float4v hi = wp[1];
#pragma unroll
      for (int e = 0; e < 4; ++e) {
        afrag[mt][kf][e]     = (_Float16)lo[e];
        afrag[mt][kf][4 + e] = (_Float16)hi[e];
      }
    }
    bias[mt] = *(const float4v*)(b2 + mtg * 16 + quad * 4);
  }

  // layer 1 for this wave's point tile, packed as B fragments
  const int pt = base + pti * 16 + n;
  const float X = x[pt * 3 + 0];
  const float Y = x[pt * 3 + 1];
  const float Z = x[pt * 3 + 2];
  half8v bf0, bf1;
#pragma unroll
  for (int j = 0; j < 8; ++j) {
    const float ha = fmaxf(fmaf(w1z[j], Z, fmaf(w1y[j], Y, fmaf(w1x[j], X, b1v[j]))), 0.f);
    const float hb = fmaxf(fmaf(w1z[8 + j], Z, fmaf(w1y[8 + j], Y, fmaf(w1x[8 + j], X, b1v[8 + j]))), 0.f);
    bf0[j] = (_Float16)ha;
    bf1[j] = (_Float16)hb;
  }

  // layer 2: 8 MFMA, epilogue relu + fp16 store
  __half* hrow = h2 + (size_t)pt * CH2;
#pragma unroll
  for (int mt = 0; mt < 4; ++mt) {
    const int mtg = mh * 4 + mt;
    float4v acc = bias[mt];
    acc = __builtin_amdgcn_mfma_f32_16x16x32_f16(afrag[mt][0], bf0, acc, 0, 0, 0);
    acc = __builtin_amdgcn_mfma_f32_16x16x32_f16(afrag[mt][1], bf1, acc, 0, 0, 0);
    const int p0 = mtg * 16 + quad * 4;
    half2v lo2, hi2;
    lo2[0] = (_Float16)fmaxf(acc[0], 0.f);
    lo2[1] = (_Float16)fmaxf(acc[1], 0.f);
    hi2[0] = (_Float16)fmaxf(acc[2], 0.f);
    hi2[1] = (_Float16)fmaxf(acc[3], 0.f);
    uint2 pk;
    pk.x = __builtin_bit_cast(unsigned, lo2);
    pk.y = __builtin_bit_cast(unsigned, hi2);
    *(uint2*)(hrow + p0) = pk;
  }
}

// ---------------------------------------------------------------------------
// Kernel 2: ball query + max-pool. One wave per query, 4 queries/block.
// Phase 1: float4 candidate loads, fp32 distance + fp64 guard band
// (decisions bit-exact vs np reference).
// Phase 2: lane = (hit-slot h, channel-slice c); 16 dwordx4 loads batched
// (no inline asm in the reduction -> scheduler can keep them in flight),
// pk-max tree + ds_swizzle butterfly.
// Writeout: block stages 4 queries x 128 ch in LDS, then emits 16-B
// coalesced segments (fixes the 2x HBM write amplification of per-lane
// scattered dword stores).
// ---------------------------------------------------------------------------
__global__ __launch_bounds__(256, 4) void query_kernel(
    const float4v* __restrict__ xyzq,
    const __half* __restrict__ h2,
    float* __restrict__ out) {
  __shared__ int list[4][NSAMP];
  __shared__ unsigned res[4][64];   // [query-slot][channel-pair]

  const int t = threadIdx.x;
  const int wave = t >> 6;
  const int lane = t & 63;
  const int s0 = blockIdx.x * 4;        // first query of this block
  const int q = s0 + wave;
  const int b = q >> 11;
  const int s = q & (NPTS - 1);

  const float4v* xq = xyzq + (size_t)b * NPTS;
  const float4v qv = xq[s];
  const float qx = qv[0], qy = qv[1], qz = qv[2], dqf = qv[3];
  const double dq = (double)qx * qx + (double)qy * qy + (double)qz * qz;
  const unsigned long long lt = (1ull << lane) - 1ull;

  // ---- Phase 1: first NSAMP in-radius hits, ascending index ----
  int count = 0;
  for (int g = 0; g < NPTS / 256 && count < NSAMP; ++g) {
    float4v pv[4];
#pragma unroll
    for (int j = 0; j < 4; ++j) pv[j] = xq[g * 256 + j * 64 + lane];
#pragma unroll
    for (int j = 0; j < 4; ++j) {
      const int m = g * 256 + j * 64 + lane;
      const float px = pv[j][0], py = pv[j][1], pz = pv[j][2];
      const float dot = fmaf(qz, pz, fmaf(qy, py, qx * px));
      const float dist = fmaf(-2.f, dot, dqf + pv[j][3]);
      bool hit;
      if (__ballot(__builtin_fabsf(dist - 0.36f) <= 3e-5f)) {
        const double dm = (double)px * px + (double)py * py + (double)pz * pz;
        const double dd = (double)qx * px + (double)qy * py + (double)qz * pz;
        hit = !((dq + dm - 2.0 * dd) > 0.36);
      } else {
        hit = !(dist > 0.36f);
      }
      const unsigned long long mask = __ballot(hit);
      if (hit) {
        const int pos = count + __popcll(mask & lt);
        if (pos < NSAMP) list[wave][pos] = m;
      }
      count += __popcll(mask);
    }
  }
  if (count > NSAMP) count = NSAMP;
  const int first = list[wave][0];      // self is always a hit
  if (lane >= count) list[wave][lane] = first;

  // ---- Phase 2: 8 hit-slots x 16 channels per lane, loads batched ----
  const int h = lane & 7;
  const int c = lane >> 3;
  const char* hb = (const char*)h2 + (size_t)b * NPTS * CH2 * 2 + c * 32;

  int ms[8];
#pragma unroll
  for (int r = 0; r < 8; ++r) ms[r] = list[wave][r * 8 + h];

  uint4v la[8], lb[8];
#pragma unroll
  for (int r = 0; r < 8; ++r) {
    const char* p = hb + (size_t)ms[r] * 256;
    la[r] = *(const uint4v*)p;
    lb[r] = *(const uint4v*)(p + 16);
  }

  // pairwise max tree over the 8 hit rows
  uint4v A = pk4max(pk4max(pk4max(la[0], la[1]), pk4max(la[2], la[3])),
                    pk4max(pk4max(la[4], la[5]), pk4max(la[6], la[7])));
  uint4v B = pk4max(pk4max(pk4max(lb[0], lb[1]), pk4max(lb[2], lb[3])),
                    pk4max(pk4max(lb[4], lb[5]), pk4max(lb[6], lb[7])));

  unsigned a0 = A[0], a1 = A[1], a2 = A[2], a3 = A[3];
  unsigned a4 = B[0], a5 = B[1], a6 = B[2], a7 = B[3];

  // xor-butterfly over hit-slot bits (lane bits 0..2)
#define RED_STEP(IMM)                                                         \
  a0 = pmax(a0, (unsigned)__builtin_amdgcn_ds_swizzle((int)a0, IMM));         \
  a1 = pmax(a1, (unsigned)__builtin_amdgcn_ds_swizzle((int)a1, IMM));         \
  a2 = pmax(a2, (unsigned)__builtin_amdgcn_ds_swizzle((int)a2, IMM));         \
  a3 = pmax(a3, (unsigned)__builtin_amdgcn_ds_swizzle((int)a3, IMM));         \
  a4 = pmax(a4, (unsigned)__builtin_amdgcn_ds_swizzle((int)a4, IMM));         \
  a5 = pmax(a5, (unsigned)__builtin_amdgcn_ds_swizzle((int)a5, IMM));         \
  a6 = pmax(a6, (unsigned)__builtin_amdgcn_ds_swizzle((int)a6, IMM));         \
  a7 = pmax(a7, (unsigned)__builtin_amdgcn_ds_swizzle((int)a7, IMM));
  RED_STEP(0x041F)   // xor 1
  RED_STEP(0x081F)   // xor 2
  RED_STEP(0x101F)   // xor 4
#undef RED_STEP

  // lane keeps half2 #h of its 16-channel slice -> channel pair index = lane
  const unsigned s1 = (h & 1) ? a1 : a0;
  const unsigned s2 = (h & 1) ? a3 : a2;
  const unsigned s3 = (h & 1) ? a5 : a4;
  const unsigned s4 = (h & 1) ? a7 : a6;
  const unsigned t1 = (h & 2) ? s2 : s1;
  const unsigned t2 = (h & 2) ? s4 : s3;
  const unsigned vsel = (h & 4) ? t2 : t1;
  res[wave][lane] = vsel;            // channels (2*lane, 2*lane+1) of query q

  __syncthreads();

  // ---- Writeout: coalesced 16-B segments across the block's 4 queries ----
  // thread t writes out[b][p][s0 + ss], ss in {2*(t&1), 2*(t&1)+1} (float2)
  {
    const int p = t >> 1;            // 0..127
    const int ss = (t & 1) * 2;      // 0 or 2
    const unsigned r0 = res[ss][p >> 1];
    const unsigned r1 = res[ss + 1][p >> 1];
    float2 w;
    w.x = (p & 1) ? h2hi(r0) : h2lo(r0);
    w.y = (p & 1) ? h2hi(r1) : h2lo(r1);
    const size_t ob = (size_t)b * CH2 * NPTS;
    *(float2*)(out + ob + (size_t)p * NPTS + (s0 & (NPTS - 1)) + ss) = w;
  }
}

// ---------------------------------------------------------------------------
extern "C" void kernel_launch(void* const* d_in, const int* in_sizes, int n_in,
                              void* d_out, int out_size, void* d_ws, size_t ws_size,
                              hipStream_t stream) {
  const float* x  = (const float*)d_in[0];
  const float* W1 = (const float*)d_in[1];
  const float* b1 = (const float*)d_in[2];
  const float* W2 = (const float*)d_in[3];
  const float* b2 = (const float*)d_in[4];
  float* out = (float*)d_out;

  __half*  h2   = (__half*)d_ws;                                     // 4 MB
  float4v* xyzq = (float4v*)((char*)d_ws + (size_t)4 * 1024 * 1024); // 256 KB

  mlp_kernel<<<(BATCH * NPTS) / 32, 256, 0, stream>>>(
      x, W1, b1, W2, b2, h2, xyzq);
  query_kernel<<<(BATCH * NPTS) / 4, 256, 0, stream>>>(xyzq, h2, out);
}